// Round 10
// baseline (1560.160 us; speedup 1.0000x reference)
//
#include <hip/hip_runtime.h>

#define TT   1024
#define SEQB 8   // 128 blocks: 8 seqs x BOTH dirs per block, 1 block/CU on 128 CUs.
                 // R6: more blocks = dup issue (1.7x loss). R8: more waves = lockstep null.
                 // R10: second dir in the SAME instruction stream fills trans/MFMA gaps.

typedef __attribute__((ext_vector_type(8))) short short8;   // 8 bf16 (MFMA A/B frag)
typedef __attribute__((ext_vector_type(4))) short short4v;  // 4 bf16 = 8B
typedef __attribute__((ext_vector_type(4))) float f32x4;    // MFMA C/D frag

#define LOG2E 1.44269504088896340736f

static __device__ __forceinline__ float sigf(float z) {
    return __builtin_amdgcn_rcpf(1.0f + __builtin_amdgcn_exp2f(-z * LOG2E));
}
static __device__ __forceinline__ float tanhf_(float z) {
    return fmaf(-2.0f, __builtin_amdgcn_rcpf(1.0f + __builtin_amdgcn_exp2f(2.0f * LOG2E * z)), 1.0f);
}
static __device__ __forceinline__ short bhi(float f) {
    return (short)(__builtin_bit_cast(unsigned, f) >> 16);
}
static __device__ __forceinline__ float fhi(float f) {
    return __builtin_bit_cast(float, __builtin_bit_cast(unsigned, f) & 0xffff0000u);
}

// Per block: fwd+bwd recurrences of the same 8 seqs, phase-shifted by half a
// step. Interval A: bwd gates(t-1) [trans/VALU] + fwd z-MFMA(t); barrier.
// Interval B: fwd gates(t) + bwd z-MFMA(t); barrier. Each dir's H buffer is
// read and written in OPPOSITE intervals -> single-buffered, race-free.
__global__ __launch_bounds__(256, 1) void bilstm_dual(
    const float* __restrict__ x,
    const float* __restrict__ Wih_f, const float* __restrict__ Whh_f,
    const float* __restrict__ bih_f, const float* __restrict__ bhh_f,
    const float* __restrict__ Wih_b, const float* __restrict__ Whh_b,
    const float* __restrict__ bih_b, const float* __restrict__ bhh_b,
    const float* __restrict__ fc_w, const float* __restrict__ fc_b,
    float* __restrict__ out)
{
    const int b0  = blockIdx.x * SEQB;
    const int tid  = threadIdx.x;
    const int w    = tid >> 6;
    const int lane = tid & 63;
    const int hb   = lane >> 4;   // K-chunk owner (A/B), row-group (C/D)
    const int n    = lane & 15;   // seq column (n>=8: quarantined, bounded garbage)
    const int nx   = n & 7;

    __shared__ short Hf[2][16][72];     // [hi/lo][seq][h-row], fwd h (single buffer)
    __shared__ short Hb[2][16][72];     // bwd h
    __shared__ float xs[SEQB][TT + 1];  // natural order; bwd indexes TT-1-t
    __shared__ float Ff[2][16][4];      // [parity][seq][wave] fwd FC partials
    __shared__ float Fb[2][16][4];      // bwd FC partials
    __shared__ float os[SEQB][TT + 1];  // per-step outputs (both dirs summed)

    for (int i = tid; i < 2 * 16 * 72 / 2; i += 256) {
        ((unsigned*)Hf)[i] = 0u;
        ((unsigned*)Hb)[i] = 0u;
    }
    for (int idx = tid; idx < SEQB * TT; idx += 256)
        xs[idx >> 10][idx & (TT - 1)] = x[(size_t)b0 * TT + idx];

    // A-fragments, both dirs: lane holds A[row=n][k=8*hb+e], hi/lo bf16 split.
    short8 ahf[4][2], alf[4][2], ahb[4][2], alb[4][2];
#define LOADA(AH, AL, WPTR)                                                      \
    _Pragma("unroll")                                                            \
    for (int s = 0; s < 4; ++s)                                                  \
        _Pragma("unroll")                                                        \
        for (int kt = 0; kt < 2; ++kt) {                                         \
            const float* p = (WPTR) + (64 * s + 16 * w + n) * 64 + 32 * kt + 8 * hb; \
            const float4 u0 = *(const float4*)p;                                 \
            const float4 u1 = *(const float4*)(p + 4);                           \
            float v[8] = {u0.x, u0.y, u0.z, u0.w, u1.x, u1.y, u1.z, u1.w};       \
            short8 h8, l8;                                                       \
            _Pragma("unroll")                                                    \
            for (int e = 0; e < 8; ++e) { h8[e] = bhi(v[e]); l8[e] = bhi(v[e] - fhi(v[e])); } \
            AH[s][kt] = h8; AL[s][kt] = l8;                                      \
        }
    LOADA(ahf, alf, Whh_f)
    LOADA(ahb, alb, Whh_b)
#undef LOADA

    f32x4 biasf[4], wihf[4], biasb[4], wihb[4], fcwf, fcwb;
#pragma unroll
    for (int s = 0; s < 4; ++s)
#pragma unroll
        for (int r = 0; r < 4; ++r) {
            const int row = 64 * s + 16 * w + 4 * hb + r;
            biasf[s][r] = bih_f[row] + bhh_f[row];
            wihf[s][r]  = Wih_f[row];
            biasb[s][r] = bih_b[row] + bhh_b[row];
            wihb[s][r]  = Wih_b[row];
        }
#pragma unroll
    for (int r = 0; r < 4; ++r) {
        fcwf[r] = fc_w[16 * w + 4 * hb + r];
        fcwb[r] = fc_w[64 + 16 * w + 4 * hb + r];
    }
    const float fcb0 = fc_b[0];

    // Pin loop-invariants (R3/R4: compiler otherwise re-sinks the loads).
    asm volatile("" : "+v"(ahf[0][0]), "+v"(ahf[0][1]), "+v"(ahf[1][0]), "+v"(ahf[1][1]),
                      "+v"(ahf[2][0]), "+v"(ahf[2][1]), "+v"(ahf[3][0]), "+v"(ahf[3][1]),
                      "+v"(alf[0][0]), "+v"(alf[0][1]), "+v"(alf[1][0]), "+v"(alf[1][1]),
                      "+v"(alf[2][0]), "+v"(alf[2][1]), "+v"(alf[3][0]), "+v"(alf[3][1]));
    asm volatile("" : "+v"(ahb[0][0]), "+v"(ahb[0][1]), "+v"(ahb[1][0]), "+v"(ahb[1][1]),
                      "+v"(ahb[2][0]), "+v"(ahb[2][1]), "+v"(ahb[3][0]), "+v"(ahb[3][1]),
                      "+v"(alb[0][0]), "+v"(alb[0][1]), "+v"(alb[1][0]), "+v"(alb[1][1]),
                      "+v"(alb[2][0]), "+v"(alb[2][1]), "+v"(alb[3][0]), "+v"(alb[3][1]));
    asm volatile("" : "+v"(biasf[0]), "+v"(biasf[1]), "+v"(biasf[2]), "+v"(biasf[3]),
                      "+v"(wihf[0]), "+v"(wihf[1]), "+v"(wihf[2]), "+v"(wihf[3]), "+v"(fcwf));
    asm volatile("" : "+v"(biasb[0]), "+v"(biasb[1]), "+v"(biasb[2]), "+v"(biasb[3]),
                      "+v"(wihb[0]), "+v"(wihb[1]), "+v"(wihb[2]), "+v"(wihb[3]), "+v"(fcwb));

    __syncthreads();

    f32x4 cf = {0.f, 0.f, 0.f, 0.f}, cb = {0.f, 0.f, 0.f, 0.f};
    f32x4 accf[4], accb[4];

    // Depth-6 MFMA chain per gate (R5-proven); 3 products: ahi*bhi, ahi*blo, alo*bhi.
#define ZMFMA(ACC, AH, AL, BF, XT, WIH, BIAS)                                            \
    _Pragma("unroll")                                                                    \
    for (int S = 0; S < 4; ++S) {                                                        \
        f32x4 a_;                                                                        \
        a_[0] = fmaf(XT, WIH[S][0], BIAS[S][0]);                                         \
        a_[1] = fmaf(XT, WIH[S][1], BIAS[S][1]);                                         \
        a_[2] = fmaf(XT, WIH[S][2], BIAS[S][2]);                                         \
        a_[3] = fmaf(XT, WIH[S][3], BIAS[S][3]);                                         \
        a_ = __builtin_amdgcn_mfma_f32_16x16x32_bf16(AH[S][0], BF[0][0], a_, 0, 0, 0);   \
        a_ = __builtin_amdgcn_mfma_f32_16x16x32_bf16(AH[S][0], BF[0][1], a_, 0, 0, 0);   \
        a_ = __builtin_amdgcn_mfma_f32_16x16x32_bf16(AL[S][0], BF[0][0], a_, 0, 0, 0);   \
        a_ = __builtin_amdgcn_mfma_f32_16x16x32_bf16(AH[S][1], BF[1][0], a_, 0, 0, 0);   \
        a_ = __builtin_amdgcn_mfma_f32_16x16x32_bf16(AH[S][1], BF[1][1], a_, 0, 0, 0);   \
        a_ = __builtin_amdgcn_mfma_f32_16x16x32_bf16(AL[S][1], BF[1][0], a_, 0, 0, 0);   \
        ACC[S] = a_;                                                                     \
    }

    // Gates + c/h update + H publish + FC partial (trans/VALU block).
#define GATES(ACC, C, HLDS, FCW, FCDST)                                                  \
    {                                                                                    \
        f32x4 hn; short4v ph, pl;                                                        \
        _Pragma("unroll")                                                                \
        for (int r = 0; r < 4; ++r) {                                                    \
            const float gi = sigf(ACC[0][r]);                                            \
            const float gf_ = sigf(ACC[1][r]);                                           \
            const float gg = tanhf_(ACC[2][r]);                                          \
            const float go = sigf(ACC[3][r]);                                            \
            C[r] = fmaf(gf_, C[r], gi * gg);                                             \
            const float hv = go * tanhf_(C[r]);                                          \
            hn[r] = hv; ph[r] = bhi(hv); pl[r] = bhi(hv - fhi(hv));                      \
        }                                                                                \
        *(short4v*)&HLDS[0][n][16 * w + 4 * hb] = ph;                                    \
        *(short4v*)&HLDS[1][n][16 * w + 4 * hb] = pl;                                    \
        float d = hn[0] * FCW[0] + hn[1] * FCW[1] + hn[2] * FCW[2] + hn[3] * FCW[3];     \
        d += __shfl_xor(d, 16);                                                          \
        d += __shfl_xor(d, 32);                                                          \
        if (lane < 16) FCDST[lane][w] = d;                                               \
    }

#pragma unroll 1
    for (int t = 0; t < TT; ++t) {
        // ---- interval A: bwd gates(t-1) interleave with fwd z-MFMA(t) ----
        short8 Bff[2][2];
#pragma unroll
        for (int kt = 0; kt < 2; ++kt) {
            Bff[kt][0] = *(const short8*)&Hf[0][n][32 * kt + 8 * hb];
            Bff[kt][1] = *(const short8*)&Hf[1][n][32 * kt + 8 * hb];
        }
        if (t) GATES(accb, cb, Hb, fcwb, Fb[(t - 1) & 1])
        {
            const float xt = xs[nx][t];
            ZMFMA(accf, ahf, alf, Bff, xt, wihf, biasf)
        }
        __syncthreads();

        // ---- interval B: fwd gates(t) interleave with bwd z-MFMA(t) ----
        short8 Bfb[2][2];
#pragma unroll
        for (int kt = 0; kt < 2; ++kt) {
            Bfb[kt][0] = *(const short8*)&Hb[0][n][32 * kt + 8 * hb];
            Bfb[kt][1] = *(const short8*)&Hb[1][n][32 * kt + 8 * hb];
        }
        GATES(accf, cf, Hf, fcwf, Ff[t & 1])
        if (t && w == 0 && lane < SEQB) {   // drain out[b, t-1] into LDS os
            const float4 pf_ = *(const float4*)&Ff[(t - 1) & 1][lane][0];
            const float4 pb_ = *(const float4*)&Fb[(t - 1) & 1][lane][0];
            os[lane][t - 1] = pf_.x + pf_.y + pf_.z + pf_.w
                            + pb_.x + pb_.y + pb_.z + pb_.w + fcb0;
        }
        {
            const float xtb = xs[nx][TT - 1 - t];   // bwd consumes x reversed
            ZMFMA(accb, ahb, alb, Bfb, xtb, wihb, biasb)
        }
        __syncthreads();
    }
#undef ZMFMA

    // Epilogue: bwd gates for t=TT-1, then final drains + bulk store.
    GATES(accb, cb, Hb, fcwb, Fb[(TT - 1) & 1])
#undef GATES
    __syncthreads();
    if (w == 0 && lane < SEQB) {
        const float4 pf_ = *(const float4*)&Ff[(TT - 1) & 1][lane][0];
        const float4 pb_ = *(const float4*)&Fb[(TT - 1) & 1][lane][0];
        os[lane][TT - 1] = pf_.x + pf_.y + pf_.z + pf_.w
                         + pb_.x + pb_.y + pb_.z + pb_.w + fcb0;
    }
    __syncthreads();

#pragma unroll
    for (int s = 0; s < SEQB; ++s) {
        const int i = tid * 4;   // 256 threads x 4 floats = one full row
        *(float4*)(out + (size_t)(b0 + s) * TT + i) = *(const float4*)&os[s][i];
    }
}

extern "C" void kernel_launch(void* const* d_in, const int* in_sizes, int n_in,
                              void* d_out, int out_size, void* d_ws, size_t ws_size,
                              hipStream_t stream) {
    const float* xp    = (const float*)d_in[0];
    const float* Wih_f = (const float*)d_in[1];
    const float* Whh_f = (const float*)d_in[2];
    const float* bih_f = (const float*)d_in[3];
    const float* bhh_f = (const float*)d_in[4];
    const float* Wih_b = (const float*)d_in[5];
    const float* Whh_b = (const float*)d_in[6];
    const float* bih_b = (const float*)d_in[7];
    const float* bhh_b = (const float*)d_in[8];
    const float* fc_w  = (const float*)d_in[9];
    const float* fc_b  = (const float*)d_in[10];
    float* outp = (float*)d_out;

    // Every out element is stored exactly once by its block: no memset needed.
    bilstm_dual<<<dim3(1024 / SEQB), dim3(256), 0, stream>>>(
        xp, Wih_f, Whh_f, bih_f, bhh_f,
        Wih_b, Whh_b, bih_b, bhh_b, fc_w, fc_b, outp);
}

// Round 12
// 842.424 us; speedup vs baseline: 1.8520x; 1.8520x over previous
//
#include <hip/hip_runtime.h>

#define TT   1024
#define TCH  128
#define SEQB 8        // 256 blocks = 1/CU. R6: more blocks = dup issue (1.7x loss);
                      // R8: more waves lockstep (null); R10: dual-stream 1-wave (2x loss).

typedef __attribute__((ext_vector_type(8))) short short8;   // 8 bf16 (MFMA A/B frag)
typedef __attribute__((ext_vector_type(4))) short short4v;  // 4 bf16 = 8B
typedef __attribute__((ext_vector_type(4))) float f32x4;    // MFMA C/D frag

#define LOG2E 1.44269504088896340736f

static __device__ __forceinline__ float sigf(float z) {
    return __builtin_amdgcn_rcpf(1.0f + __builtin_amdgcn_exp2f(-z * LOG2E));
}
static __device__ __forceinline__ float tanhf_(float z) {
    return fmaf(-2.0f, __builtin_amdgcn_rcpf(1.0f + __builtin_amdgcn_exp2f(2.0f * LOG2E * z)), 1.0f);
}
static __device__ __forceinline__ short bhi(float f) {
    return (short)(__builtin_bit_cast(unsigned, f) >> 16);
}
static __device__ __forceinline__ float fhi(float f) {
    return __builtin_bit_cast(float, __builtin_bit_cast(unsigned, f) & 0xffff0000u);
}

// R9 structure (805us anchor: MFMA z, LDS os, no atomics) + R11 changes:
//  (1) gates/pack/FC predicated on n<8 -- counter model says the step wall is
//      the transcendental segment (~640 cyc/step at ~16cyc/wave64 trans) and
//      HALF of it was garbage-column work. EXEC-masked lanes may halve it.
//  (2) depth-3 dual-accumulator MFMA chains (shorter exposed tail).
// Garbage Hlds columns (seq 8..15) are zero-init'd and never written.
__global__ __launch_bounds__(256, 2) void bilstm_mfma(
    const float* __restrict__ x,
    const float* __restrict__ Wih_f, const float* __restrict__ Whh_f,
    const float* __restrict__ bih_f, const float* __restrict__ bhh_f,
    const float* __restrict__ Wih_b, const float* __restrict__ Whh_b,
    const float* __restrict__ bih_b, const float* __restrict__ bhh_b,
    const float* __restrict__ fc_w, const float* __restrict__ fc_b,
    float* __restrict__ out, float* __restrict__ ws)
{
    const int dir = blockIdx.x & 1;
    const int b0  = (blockIdx.x >> 1) * SEQB;
    const int tid  = threadIdx.x;
    const int w    = tid >> 6;
    const int lane = tid & 63;
    const int hb   = lane >> 4;   // K-chunk owner (A/B), row-group (C/D)
    const int n    = lane & 15;   // seq column (n>=8: garbage cols, gates skipped)

    const float* __restrict__ Whh = dir ? Whh_b : Whh_f;
    const float* __restrict__ Wih = dir ? Wih_b : Wih_f;
    const float* __restrict__ bih = dir ? bih_b : bih_f;
    const float* __restrict__ bhh = dir ? bhh_b : bhh_f;

    __shared__ short Hlds[2][2][16][72];   // [buf][hi/lo][seq][h-row], 144B rows
    __shared__ float xs[16][TCH + 1];      // stride 129: conflict-free column read
    __shared__ float fcfb[2][16][4];       // [parity][seq][wave] FC partials
    __shared__ float os[SEQB][TT + 1];     // per-step FC results (LDS, no atomics)

    // Zero H (both buffers; garbage cols stay 0 forever) and xs rows 8..15.
    {
        unsigned* p1 = (unsigned*)&Hlds[0][0][0][0];
        for (int i = tid; i < 2 * 2 * 16 * 72 / 2; i += 256) p1[i] = 0u;
        float* p2 = &xs[SEQB][0];
        for (int i = tid; i < (16 - SEQB) * (TCH + 1); i += 256) p2[i] = 0.f;
    }

    // A-fragments: lane holds A[row=lane&15][k=8*(lane>>4)+e], hi/lo bf16 split.
    short8 ahi[4][2], alo[4][2];
#pragma unroll
    for (int s = 0; s < 4; ++s)
#pragma unroll
        for (int kt = 0; kt < 2; ++kt) {
            const int zrow = 64 * s + 16 * w + n;
            const float* p = Whh + zrow * 64 + 32 * kt + 8 * hb;
            const float4 u0 = *(const float4*)p;
            const float4 u1 = *(const float4*)(p + 4);
            float v[8] = {u0.x, u0.y, u0.z, u0.w, u1.x, u1.y, u1.z, u1.w};
            short8 h8, l8;
#pragma unroll
            for (int e = 0; e < 8; ++e) {
                h8[e] = bhi(v[e]);
                l8[e] = bhi(v[e] - fhi(v[e]));
            }
            ahi[s][kt] = h8;
            alo[s][kt] = l8;
        }

    f32x4 biasv[4], wihv[4], fcwv;
#pragma unroll
    for (int s = 0; s < 4; ++s)
#pragma unroll
        for (int r = 0; r < 4; ++r) {
            const int row = 64 * s + 16 * w + 4 * hb + r;
            biasv[s][r] = bih[row] + bhh[row];
            wihv[s][r]  = Wih[row];
        }
#pragma unroll
    for (int r = 0; r < 4; ++r) fcwv[r] = fc_w[dir * 64 + 16 * w + 4 * hb + r];
    const float fcbv = dir ? 0.f : fc_b[0];

    // Pin loop-invariant fragments (R3/R4: compiler otherwise re-sinks loads).
    asm volatile("" : "+v"(ahi[0][0]), "+v"(ahi[0][1]), "+v"(ahi[1][0]), "+v"(ahi[1][1]),
                      "+v"(ahi[2][0]), "+v"(ahi[2][1]), "+v"(ahi[3][0]), "+v"(ahi[3][1]),
                      "+v"(alo[0][0]), "+v"(alo[0][1]), "+v"(alo[1][0]), "+v"(alo[1][1]),
                      "+v"(alo[2][0]), "+v"(alo[2][1]), "+v"(alo[3][0]), "+v"(alo[3][1]));
    asm volatile("" : "+v"(biasv[0]), "+v"(biasv[1]), "+v"(biasv[2]), "+v"(biasv[3]),
                      "+v"(wihv[0]), "+v"(wihv[1]), "+v"(wihv[2]), "+v"(wihv[3]), "+v"(fcwv));

    // First x tile. Bwd consumes x reversed; out index stays t.
    for (int idx = tid; idx < SEQB * TCH; idx += 256) {
        const int s = idx >> 7, i = idx & (TCH - 1);
        const int src = dir ? (TT - 1 - i) : i;
        xs[s][i] = x[(size_t)(b0 + s) * TT + src];
    }
    __syncthreads();

    f32x4 c = {0.f, 0.f, 0.f, 0.f};
    int cur = 0;

#pragma unroll 1
    for (int t = 0; t < TT; ++t) {
        if (t && (t & (TCH - 1)) == 0) {   // refill x tile (8x per kernel)
            for (int idx = tid; idx < SEQB * TCH; idx += 256) {
                const int s = idx >> 7, i = idx & (TCH - 1);
                const int tg = t + i;
                const int src = dir ? (TT - 1 - tg) : tg;
                xs[s][i] = x[(size_t)(b0 + s) * TT + src];
            }
            __syncthreads();
        }
        // Drain previous step's FC partials into os (LDS; no vmem in loop).
        if (t && w == 0 && lane < SEQB) {
            const float4 fp = *(const float4*)&fcfb[(t - 1) & 1][lane][0];
            os[lane][t - 1] = fp.x + fp.y + fp.z + fp.w + fcbv;
        }

        // B-fragments: lane holds B[k=8*(lane>>4)+e][n=lane&15]; 1 b128/frag.
        short8 Bf[2][2];
#pragma unroll
        for (int kt = 0; kt < 2; ++kt)
#pragma unroll
            for (int pp = 0; pp < 2; ++pp)
                Bf[kt][pp] = *(const short8*)&Hlds[cur][pp][n][32 * kt + 8 * hb];

        const float xt = xs[n][t & (TCH - 1)];

        // Two depth-3 chains per gate (shorter exposed MFMA tail than depth-6).
        f32x4 acc0, acc1, acc2, acc3;
#define ZCHAIN(ACC, S)                                                                    \
        ACC[0] = fmaf(xt, wihv[S][0], biasv[S][0]);                                       \
        ACC[1] = fmaf(xt, wihv[S][1], biasv[S][1]);                                       \
        ACC[2] = fmaf(xt, wihv[S][2], biasv[S][2]);                                       \
        ACC[3] = fmaf(xt, wihv[S][3], biasv[S][3]);                                       \
        {                                                                                 \
            f32x4 q = {0.f, 0.f, 0.f, 0.f};                                               \
            ACC = __builtin_amdgcn_mfma_f32_16x16x32_bf16(ahi[S][0], Bf[0][0], ACC, 0, 0, 0); \
            q   = __builtin_amdgcn_mfma_f32_16x16x32_bf16(ahi[S][1], Bf[1][0], q,   0, 0, 0); \
            ACC = __builtin_amdgcn_mfma_f32_16x16x32_bf16(ahi[S][0], Bf[0][1], ACC, 0, 0, 0); \
            q   = __builtin_amdgcn_mfma_f32_16x16x32_bf16(ahi[S][1], Bf[1][1], q,   0, 0, 0); \
            ACC = __builtin_amdgcn_mfma_f32_16x16x32_bf16(alo[S][0], Bf[0][0], ACC, 0, 0, 0); \
            q   = __builtin_amdgcn_mfma_f32_16x16x32_bf16(alo[S][1], Bf[1][0], q,   0, 0, 0); \
            ACC[0] += q[0]; ACC[1] += q[1]; ACC[2] += q[2]; ACC[3] += q[3];               \
        }
        ZCHAIN(acc0, 0)   // gate i
        ZCHAIN(acc1, 1)   // gate f
        ZCHAIN(acc2, 2)   // gate g
        ZCHAIN(acc3, 3)   // gate o
#undef ZCHAIN

        // Gates + state update: ONLY real columns (n<8). Garbage lanes are
        // EXEC-masked off -- probe: does the quarter-rate trans segment scale
        // with active lanes? Garbage Hlds cols stay 0 (never written).
        if (n < SEQB) {
            f32x4 hnew;
            short4v ph, pl;
#pragma unroll
            for (int r = 0; r < 4; ++r) {
                const float gi = sigf(acc0[r]);
                const float gf = sigf(acc1[r]);
                const float gg = tanhf_(acc2[r]);
                const float go = sigf(acc3[r]);
                c[r] = fmaf(gf, c[r], gi * gg);
                const float hv = go * tanhf_(c[r]);
                hnew[r] = hv;
                ph[r] = bhi(hv);
                pl[r] = bhi(hv - fhi(hv));
            }
            *(short4v*)&Hlds[cur ^ 1][0][n][16 * w + 4 * hb] = ph;
            *(short4v*)&Hlds[cur ^ 1][1][n][16 * w + 4 * hb] = pl;

            // FC partial; shfl partners are (hb^1,n),(hb^2,n): same n, all active.
            float d = hnew[0] * fcwv[0] + hnew[1] * fcwv[1]
                    + hnew[2] * fcwv[2] + hnew[3] * fcwv[3];
            d += __shfl_xor(d, 16);
            d += __shfl_xor(d, 32);
            if (hb == 0) fcfb[t & 1][n][w] = d;
        }

        __syncthreads();
        cur ^= 1;
    }

    // Final step's FC drain, then bulk-store os -> dst (coalesced float4).
    if (w == 0 && lane < SEQB) {
        const float4 fp = *(const float4*)&fcfb[(TT - 1) & 1][lane][0];
        os[lane][TT - 1] = fp.x + fp.y + fp.z + fp.w + fcbv;
    }
    __syncthreads();

    float* __restrict__ dst = dir ? ws : out;
#pragma unroll
    for (int s = 0; s < SEQB; ++s) {
        const int i = tid * 4;   // 256 threads x 4 floats = one full row
        *(float4*)(dst + (size_t)(b0 + s) * TT + i) = *(const float4*)&os[s][i];
    }
}

__global__ __launch_bounds__(256) void add_dirs(float* __restrict__ out,
                                                const float* __restrict__ ws, int n4) {
    const int i = (blockIdx.x * 256 + threadIdx.x);
    if (i < n4) {
        float4 a = ((const float4*)out)[i];
        const float4 b = ((const float4*)ws)[i];
        a.x += b.x; a.y += b.y; a.z += b.z; a.w += b.w;
        ((float4*)out)[i] = a;
    }
}

extern "C" void kernel_launch(void* const* d_in, const int* in_sizes, int n_in,
                              void* d_out, int out_size, void* d_ws, size_t ws_size,
                              hipStream_t stream) {
    const float* xp    = (const float*)d_in[0];
    const float* Wih_f = (const float*)d_in[1];
    const float* Whh_f = (const float*)d_in[2];
    const float* bih_f = (const float*)d_in[3];
    const float* bhh_f = (const float*)d_in[4];
    const float* Wih_b = (const float*)d_in[5];
    const float* Whh_b = (const float*)d_in[6];
    const float* bih_b = (const float*)d_in[7];
    const float* bhh_b = (const float*)d_in[8];
    const float* fc_w  = (const float*)d_in[9];
    const float* fc_b  = (const float*)d_in[10];
    float* outp = (float*)d_out;
    float* wsp  = (float*)d_ws;   // bwd-direction partials (fully written before read)

    // No memset needed: fwd blocks store every out element; bwd fully writes ws.
    bilstm_mfma<<<dim3((1024 / SEQB) * 2), dim3(256), 0, stream>>>(
        xp, Wih_f, Whh_f, bih_f, bhh_f,
        Wih_b, Whh_b, bih_b, bhh_b, fc_w, fc_b, outp, wsp);

    const int n4 = out_size / 4;   // 1M floats -> 256K float4s
    add_dirs<<<dim3((n4 + 255) / 256), dim3(256), 0, stream>>>(outp, wsp, n4);
}

// Round 13
// 744.377 us; speedup vs baseline: 2.0959x; 1.1317x over previous
//
#include <hip/hip_runtime.h>

#define TT   1024
#define TCH  128
#define SEQB 8        // 256 blocks = 1/CU. R6: more blocks = dup issue (1.7x loss);
                      // R8: more waves lockstep (null); R10: dual-stream 1-wave (2x);
                      // R12: EXEC-masking lanes is free-of-benefit -> cut INSTRUCTIONS.

typedef __attribute__((ext_vector_type(8))) short short8;   // 8 bf16 (MFMA A/B frag)
typedef __attribute__((ext_vector_type(4))) float f32x4;    // MFMA C/D frag

#define LOG2E 1.44269504088896340736f

static __device__ __forceinline__ float sigf(float z) {
    return __builtin_amdgcn_rcpf(1.0f + __builtin_amdgcn_exp2f(-z * LOG2E));
}
static __device__ __forceinline__ float tanhf_(float z) {
    return fmaf(-2.0f, __builtin_amdgcn_rcpf(1.0f + __builtin_amdgcn_exp2f(2.0f * LOG2E * z)), 1.0f);
}
static __device__ __forceinline__ float fhi(float f) {
    return __builtin_bit_cast(float, __builtin_bit_cast(unsigned, f) & 0xffff0000u);
}

// R9 structure (805us anchor) + R13: pair-lane activation split.
// After the z-MFMAs, lane L=16*hb+n (n>=8 = garbage tile column) takes over
// the r=2,3 accumulator slots of partner lane L^8 via in-wave shfl_xor(8).
// Every lane then runs TWO (i,f,g,o,c,h) tuples instead of four: the
// activation segment (the measured issue wall) halves its instruction count.
// c[2],c[3] live permanently on the partner lane. Exact same arithmetic.
__global__ __launch_bounds__(256, 2) void bilstm_mfma(
    const float* __restrict__ x,
    const float* __restrict__ Wih_f, const float* __restrict__ Whh_f,
    const float* __restrict__ bih_f, const float* __restrict__ bhh_f,
    const float* __restrict__ Wih_b, const float* __restrict__ Whh_b,
    const float* __restrict__ bih_b, const float* __restrict__ bhh_b,
    const float* __restrict__ fc_w, const float* __restrict__ fc_b,
    float* __restrict__ out, float* __restrict__ ws)
{
    const int dir = blockIdx.x & 1;
    const int b0  = (blockIdx.x >> 1) * SEQB;
    const int tid  = threadIdx.x;
    const int w    = tid >> 6;
    const int lane = tid & 63;
    const int hb   = lane >> 4;     // K-chunk owner (A/B), row-group (C/D)
    const int n    = lane & 15;     // tile column; n>=8 = activation helper lane
    const bool own = (n < SEQB);    // owns a real sequence column
    const int col  = n & 7;         // the real seq this lane's activations serve
    const int rsel = (n >> 3) << 1; // 0 for owner (r=0,1), 2 for helper (r=2,3)

    const float* __restrict__ Whh = dir ? Whh_b : Whh_f;
    const float* __restrict__ Wih = dir ? Wih_b : Wih_f;
    const float* __restrict__ bih = dir ? bih_b : bih_f;
    const float* __restrict__ bhh = dir ? bhh_b : bhh_f;

    __shared__ short Hlds[2][2][16][72];   // [buf][hi/lo][seq][h-row], 144B rows
    __shared__ float xs[16][TCH + 1];      // stride 129: conflict-free column read
    __shared__ float fcfb[2][16][4];       // [parity][seq][wave] FC partials
    __shared__ float os[SEQB][TT + 1];     // per-step FC results (LDS, no atomics)

    // Zero H (both buffers; garbage cols 8..15 stay 0 forever) and xs rows 8..15.
    {
        unsigned* p1 = (unsigned*)&Hlds[0][0][0][0];
        for (int i = tid; i < 2 * 2 * 16 * 72 / 2; i += 256) p1[i] = 0u;
        float* p2 = &xs[SEQB][0];
        for (int i = tid; i < (16 - SEQB) * (TCH + 1); i += 256) p2[i] = 0.f;
    }

    // A-fragments: lane holds A[row=lane&15][k=8*(lane>>4)+e], hi/lo bf16 split.
    short8 ahi[4][2], alo[4][2];
#pragma unroll
    for (int s = 0; s < 4; ++s)
#pragma unroll
        for (int kt = 0; kt < 2; ++kt) {
            const int zrow = 64 * s + 16 * w + n;
            const float* p = Whh + zrow * 64 + 32 * kt + 8 * hb;
            const float4 u0 = *(const float4*)p;
            const float4 u1 = *(const float4*)(p + 4);
            float v[8] = {u0.x, u0.y, u0.z, u0.w, u1.x, u1.y, u1.z, u1.w};
            short8 h8, l8;
#pragma unroll
            for (int e = 0; e < 8; ++e) {
                const unsigned b = __builtin_bit_cast(unsigned, v[e]);
                h8[e] = (short)(b >> 16);
                l8[e] = (short)(__builtin_bit_cast(unsigned, v[e] - fhi(v[e])) >> 16);
            }
            ahi[s][kt] = h8;
            alo[s][kt] = l8;
        }

    f32x4 biasv[4], wihv[4];
#pragma unroll
    for (int s = 0; s < 4; ++s)
#pragma unroll
        for (int r = 0; r < 4; ++r) {
            const int row = 64 * s + 16 * w + 4 * hb + r;
            biasv[s][r] = bih[row] + bhh[row];
            wihv[s][r]  = Wih[row];
        }
    // FC weights for THIS lane's two r-slots (owner: r=0,1; helper: r=2,3).
    const float fcw0 = fc_w[dir * 64 + 16 * w + 4 * hb + rsel + 0];
    const float fcw1 = fc_w[dir * 64 + 16 * w + 4 * hb + rsel + 1];
    const float fcbv = dir ? 0.f : fc_b[0];

    // Pin loop-invariant fragments (R3/R4: compiler otherwise re-sinks loads).
    asm volatile("" : "+v"(ahi[0][0]), "+v"(ahi[0][1]), "+v"(ahi[1][0]), "+v"(ahi[1][1]),
                      "+v"(ahi[2][0]), "+v"(ahi[2][1]), "+v"(ahi[3][0]), "+v"(ahi[3][1]),
                      "+v"(alo[0][0]), "+v"(alo[0][1]), "+v"(alo[1][0]), "+v"(alo[1][1]),
                      "+v"(alo[2][0]), "+v"(alo[2][1]), "+v"(alo[3][0]), "+v"(alo[3][1]));
    asm volatile("" : "+v"(biasv[0]), "+v"(biasv[1]), "+v"(biasv[2]), "+v"(biasv[3]),
                      "+v"(wihv[0]), "+v"(wihv[1]), "+v"(wihv[2]), "+v"(wihv[3]));

    // First x tile. Bwd consumes x reversed; out index stays t.
    for (int idx = tid; idx < SEQB * TCH; idx += 256) {
        const int s = idx >> 7, i = idx & (TCH - 1);
        const int src = dir ? (TT - 1 - i) : i;
        xs[s][i] = x[(size_t)(b0 + s) * TT + src];
    }
    __syncthreads();

    float cA = 0.f, cB = 0.f;   // this lane's two c slots (owner r=0,1 / helper r=2,3)
    int cur = 0;

#pragma unroll 1
    for (int t = 0; t < TT; ++t) {
        if (t && (t & (TCH - 1)) == 0) {   // refill x tile (8x per kernel)
            for (int idx = tid; idx < SEQB * TCH; idx += 256) {
                const int s = idx >> 7, i = idx & (TCH - 1);
                const int tg = t + i;
                const int src = dir ? (TT - 1 - tg) : tg;
                xs[s][i] = x[(size_t)(b0 + s) * TT + src];
            }
            __syncthreads();
        }
        // Drain previous step's FC partials into os (LDS; no vmem in loop).
        if (t && w == 0 && lane < SEQB) {
            const float4 fp = *(const float4*)&fcfb[(t - 1) & 1][lane][0];
            os[lane][t - 1] = fp.x + fp.y + fp.z + fp.w + fcbv;
        }

        // B-fragments: lane holds B[k=8*(lane>>4)+e][n=lane&15]; 1 b128/frag.
        short8 Bf[2][2];
#pragma unroll
        for (int kt = 0; kt < 2; ++kt)
#pragma unroll
            for (int pp = 0; pp < 2; ++pp)
                Bf[kt][pp] = *(const short8*)&Hlds[cur][pp][n][32 * kt + 8 * hb];

        const float xt = xs[n][t & (TCH - 1)];

        // Depth-6 MFMA chain per gate (R5/R9-proven).
        f32x4 acc0, acc1, acc2, acc3;
#define ZCHAIN(ACC, S)                                                              \
        ACC[0] = fmaf(xt, wihv[S][0], biasv[S][0]);                                 \
        ACC[1] = fmaf(xt, wihv[S][1], biasv[S][1]);                                 \
        ACC[2] = fmaf(xt, wihv[S][2], biasv[S][2]);                                 \
        ACC[3] = fmaf(xt, wihv[S][3], biasv[S][3]);                                 \
        ACC = __builtin_amdgcn_mfma_f32_16x16x32_bf16(ahi[S][0], Bf[0][0], ACC, 0, 0, 0); \
        ACC = __builtin_amdgcn_mfma_f32_16x16x32_bf16(ahi[S][0], Bf[0][1], ACC, 0, 0, 0); \
        ACC = __builtin_amdgcn_mfma_f32_16x16x32_bf16(alo[S][0], Bf[0][0], ACC, 0, 0, 0); \
        ACC = __builtin_amdgcn_mfma_f32_16x16x32_bf16(ahi[S][1], Bf[1][0], ACC, 0, 0, 0); \
        ACC = __builtin_amdgcn_mfma_f32_16x16x32_bf16(ahi[S][1], Bf[1][1], ACC, 0, 0, 0); \
        ACC = __builtin_amdgcn_mfma_f32_16x16x32_bf16(alo[S][1], Bf[1][0], ACC, 0, 0, 0);
        ZCHAIN(acc0, 0)   // gate i
        ZCHAIN(acc1, 1)   // gate f
        ZCHAIN(acc2, 2)   // gate g
        ZCHAIN(acc3, 3)   // gate o
#undef ZCHAIN

        // --- R13 pair-lane activation split (all 64 lanes do real work) ---
        // Helper lane L^8 receives owner's r=2,3 z-slots; selects its pair.
        const float ri0 = __shfl_xor(acc0[2], 8), ri1 = __shfl_xor(acc0[3], 8);
        const float rf0 = __shfl_xor(acc1[2], 8), rf1 = __shfl_xor(acc1[3], 8);
        const float rg0 = __shfl_xor(acc2[2], 8), rg1 = __shfl_xor(acc2[3], 8);
        const float ro0 = __shfl_xor(acc3[2], 8), ro1 = __shfl_xor(acc3[3], 8);
        const float ziA = own ? acc0[0] : ri0, ziB = own ? acc0[1] : ri1;
        const float zfA = own ? acc1[0] : rf0, zfB = own ? acc1[1] : rf1;
        const float zgA = own ? acc2[0] : rg0, zgB = own ? acc2[1] : rg1;
        const float zoA = own ? acc3[0] : ro0, zoB = own ? acc3[1] : ro1;

        const float giA = sigf(ziA), gfA = sigf(zfA), ggA = tanhf_(zgA), goA = sigf(zoA);
        const float giB = sigf(ziB), gfB = sigf(zfB), ggB = tanhf_(zgB), goB = sigf(zoB);
        cA = fmaf(gfA, cA, giA * ggA);
        cB = fmaf(gfB, cB, giB * ggB);
        const float hA = goA * tanhf_(cA);
        const float hB = goB * tanhf_(cB);

        // Pack this lane's two bf16 rows (hi and lo split) into one u32 each.
        const unsigned bhA = __builtin_bit_cast(unsigned, hA);
        const unsigned bhB = __builtin_bit_cast(unsigned, hB);
        const unsigned uph = (bhA >> 16) | (bhB & 0xffff0000u);
        const float lAv = hA - fhi(hA), lBv = hB - fhi(hB);
        const unsigned upl = (__builtin_bit_cast(unsigned, lAv) >> 16)
                           | (__builtin_bit_cast(unsigned, lBv) & 0xffff0000u);
        const int nxt = cur ^ 1;
        const int rowo = 16 * w + 4 * hb + rsel;   // even -> 4B-aligned
        *(unsigned*)&Hlds[nxt][0][col][rowo] = uph;
        *(unsigned*)&Hlds[nxt][1][col][rowo] = upl;

        // FC partial: each lane contributes its two rows; xor-8 folds the
        // r-split pair, then xor-16/32 fold the hb groups.
        float d = hA * fcw0 + hB * fcw1;
        d += __shfl_xor(d, 8);
        d += __shfl_xor(d, 16);
        d += __shfl_xor(d, 32);
        if (own && hb == 0) fcfb[t & 1][n][w] = d;

        __syncthreads();
        cur = nxt;
    }

    // Final step's FC drain, then bulk-store os -> dst (coalesced float4).
    if (w == 0 && lane < SEQB) {
        const float4 fp = *(const float4*)&fcfb[(TT - 1) & 1][lane][0];
        os[lane][TT - 1] = fp.x + fp.y + fp.z + fp.w + fcbv;
    }
    __syncthreads();

    float* __restrict__ dst = dir ? ws : out;
#pragma unroll
    for (int s = 0; s < SEQB; ++s) {
        const int i = tid * 4;   // 256 threads x 4 floats = one full row
        *(float4*)(dst + (size_t)(b0 + s) * TT + i) = *(const float4*)&os[s][i];
    }
}

__global__ __launch_bounds__(256) void add_dirs(float* __restrict__ out,
                                                const float* __restrict__ ws, int n4) {
    const int i = (blockIdx.x * 256 + threadIdx.x);
    if (i < n4) {
        float4 a = ((const float4*)out)[i];
        const float4 b = ((const float4*)ws)[i];
        a.x += b.x; a.y += b.y; a.z += b.z; a.w += b.w;
        ((float4*)out)[i] = a;
    }
}

extern "C" void kernel_launch(void* const* d_in, const int* in_sizes, int n_in,
                              void* d_out, int out_size, void* d_ws, size_t ws_size,
                              hipStream_t stream) {
    const float* xp    = (const float*)d_in[0];
    const float* Wih_f = (const float*)d_in[1];
    const float* Whh_f = (const float*)d_in[2];
    const float* bih_f = (const float*)d_in[3];
    const float* bhh_f = (const float*)d_in[4];
    const float* Wih_b = (const float*)d_in[5];
    const float* Whh_b = (const float*)d_in[6];
    const float* bih_b = (const float*)d_in[7];
    const float* bhh_b = (const float*)d_in[8];
    const float* fc_w  = (const float*)d_in[9];
    const float* fc_b  = (const float*)d_in[10];
    float* outp = (float*)d_out;
    float* wsp  = (float*)d_ws;   // bwd-direction partials (fully written before read)

    // No memset needed: fwd blocks store every out element; bwd fully writes ws.
    bilstm_mfma<<<dim3((1024 / SEQB) * 2), dim3(256), 0, stream>>>(
        xp, Wih_f, Whh_f, bih_f, bhh_f,
        Wih_b, Whh_b, bih_b, bhh_b, fc_w, fc_b, outp, wsp);

    const int n4 = out_size / 4;   // 1M floats -> 256K float4s
    add_dirs<<<dim3((n4 + 255) / 256), dim3(256), 0, stream>>>(outp, wsp, n4);
}